// Round 7
// baseline (533.096 us; speedup 1.0000x reference)
//
#include <hip/hip_runtime.h>

#define HID 2048
#define INTER 5632
#define KVW 256
#define NL 6
#define RMS_EPS 1e-6f

#define NB 256     // 1 block per CU (121KB LDS forces exclusivity anyway)
#define NT 1024    // 16 waves

typedef unsigned int uint;

// ---- barrier counter lines in ws (uint units; 1 line = 64 uints = 256B) ----
// Separate monotonic groups per barrier slot (required for arrive-early/
// wait-late: mixed-phase arrivals on a shared counter would release early).
#define LG0 0          // 16 lines: partial scores ready     (256 arrivals/layer)
#define LG2 16         // 16 lines: h' ready (post-P3)       (256/layer)
#define LG3 32         // 16 lines: inter ready (post-P4)    (256/layer)
#define LG4 48         // 16 lines: h'' ready (post-P5)      (256/layer)
#define LN1 64         // 1 line:  ctx ready                 (32/layer)
#define LNM 65         // 1 line:  attn mini (partial2 ready)(32/layer)
#define BAR_UINTS 8192

// ---- ws float offsets ----
#define F_H     8192
#define F_CTX   10240
#define F_PART  12288    // 256*256
#define F_PART2 77824    // 32*256
#define F_INTER 86016    // 5632
#define F_GSC   91648

// force value into a register NOW and forbid rematerialization later
#define PIN4(v) asm volatile("" : "+v"((v).x), "+v"((v).y), "+v"((v).z), "+v"((v).w))

// ---------------- LLC (relaxed agent-scope) access ----------------
__device__ __forceinline__ float ld_llc(const float* p) {
    return __hip_atomic_load(p, __ATOMIC_RELAXED, __HIP_MEMORY_SCOPE_AGENT);
}
__device__ __forceinline__ void st_llc(float* p, float v) {
    __hip_atomic_store(p, v, __ATOMIC_RELAXED, __HIP_MEMORY_SCOPE_AGENT);
}

// ---------------- wave helpers ----------------
__device__ __forceinline__ float waveAllSum(float v) {
#pragma unroll
    for (int m = 32; m > 0; m >>= 1) v += __shfl_xor(v, m, 64);
    return v;
}
__device__ __forceinline__ float waveAllMax(float v) {
#pragma unroll
    for (int m = 32; m > 0; m >>= 1) v = fmaxf(v, __shfl_xor(v, m, 64));
    return v;
}
__device__ __forceinline__ float dot4(float4 a, float4 b, float acc) {
    acc = fmaf(a.x, b.x, acc);
    acc = fmaf(a.y, b.y, acc);
    acc = fmaf(a.z, b.z, acc);
    acc = fmaf(a.w, b.w, acc);
    return acc;
}

// ---------------- split monotonic barriers ----------------
// __syncthreads in arrive drains vmcnt, so this block's sc1 data stores are at
// the LLC before the arrival add; waiters poll the arrival lines directly.
__device__ __forceinline__ void arrive_grp(uint* bar, int grp, int bid) {
    __syncthreads();
    if (threadIdx.x == 0)
        __hip_atomic_fetch_add(bar + (grp + (bid & 15)) * 64, 1u,
                               __ATOMIC_RELAXED, __HIP_MEMORY_SCOPE_AGENT);
}
__device__ __forceinline__ void wait_grp(const uint* bar, int grp, uint target) {
    if (threadIdx.x < 16) {
        const uint* p = bar + (grp + threadIdx.x) * 64;
        while (true) {
            uint v = __hip_atomic_load(p, __ATOMIC_RELAXED, __HIP_MEMORY_SCOPE_AGENT);
#pragma unroll
            for (int m = 8; m > 0; m >>= 1) v += __shfl_xor(v, m, 64);
            if (v >= target) break;
            __builtin_amdgcn_s_sleep(16);
        }
    }
    __syncthreads();
}
__device__ __forceinline__ void arrive_line(uint* bar, int line) {
    __syncthreads();
    if (threadIdx.x == 0)
        __hip_atomic_fetch_add(bar + line * 64, 1u, __ATOMIC_RELAXED, __HIP_MEMORY_SCOPE_AGENT);
}
template <int SLP>
__device__ __forceinline__ void wait_line(const uint* bar, int line, uint target) {
    if (threadIdx.x == 0) {
        while (__hip_atomic_load(bar + line * 64, __ATOMIC_RELAXED, __HIP_MEMORY_SCOPE_AGENT) < target)
            __builtin_amdgcn_s_sleep(SLP);
    }
    __syncthreads();
}

// rmsnorm(h, nw) -> xbuf[2048]; aux[0..16) scratch
__device__ __forceinline__ void block_rms_norm(const float* __restrict__ h,
                                               const float* __restrict__ nw,
                                               float* xbuf, float* aux) {
    const int tid = threadIdx.x, lane = tid & 63, wid = tid >> 6;
    const float a = ld_llc(h + 2 * tid), b = ld_llc(h + 2 * tid + 1);
    float ss = a * a + b * b;
    ss = waveAllSum(ss);
    if (lane == 0) aux[wid] = ss;
    __syncthreads();
    float tot = 0.f;
#pragma unroll
    for (int i = 0; i < 16; ++i) tot += aux[i];
    const float f = rsqrtf(tot * (1.0f / (float)HID) + RMS_EPS);
    xbuf[2 * tid]     = a * f * nw[2 * tid];
    xbuf[2 * tid + 1] = b * f * nw[2 * tid + 1];
    __syncthreads();
}

// ---------------- init ----------------
__global__ __launch_bounds__(1024) void k_init(const float* __restrict__ x,
                                               float* __restrict__ ws) {
    uint* bar = (uint*)ws;
#pragma unroll
    for (int k = 0; k < 8; ++k) bar[k * 1024 + threadIdx.x] = 0u;
    float* h = ws + F_H;
    h[threadIdx.x] = x[threadIdx.x];
    h[1024 + threadIdx.x] = x[1024 + threadIdx.x];
}

// ---------------- persistent backbone ----------------
__global__ __launch_bounds__(NT) __attribute__((amdgpu_waves_per_eu(4, 4)))
void k_backbone(
    const float* __restrict__ kvw,
    const float* __restrict__ n1w, const float* __restrict__ n2w,
    const float* __restrict__ q_w, const float* __restrict__ o_w,
    const float* __restrict__ shg_w,
    const float* __restrict__ g_w, const float* __restrict__ u_w,
    const float* __restrict__ dn_w,
    float* __restrict__ out, float* __restrict__ ws) {
    __shared__ float pf[12 * 2048];   // 96KB Wg/Wu prefetch (12 of 44 row-tasks)
    __shared__ float buf[5632];
    __shared__ float aux[64];

    uint*  bar      = (uint*)ws;
    float* h        = ws + F_H;
    float* ctx      = ws + F_CTX;
    float* partial  = ws + F_PART;
    float* partial2 = ws + F_PART2;
    float* inter    = ws + F_INTER;
    float* gsc      = ws + F_GSC;

    const int bid  = blockIdx.x;
    const int tid  = threadIdx.x;
    const int lane = tid & 63, wid = tid >> 6;
    const int row8 = bid * 8 + (wid >> 1);   // this block's 8 hidden rows
    const int half = wid & 1;
    const int j256 = tid & 255, grp = tid >> 8;

    // layer-0 Wq rows, pinned
    float4 qpre[4];
    {
        const float4* Qn = (const float4*)(q_w + (size_t)row8 * HID + half * 1024);
#pragma unroll
        for (int k = 0; k < 4; ++k) { qpre[k] = Qn[k * 64 + lane]; PIN4(qpre[k]); }
    }

    for (int L = 0; L < NL; ++L) {
        const float* Wo = o_w  + (size_t)L * HID * HID;
        const float* Wg = g_w  + (size_t)L * INTER * HID;
        const float* Wu = u_w  + (size_t)L * INTER * HID;
        const float* Wd = dn_w + (size_t)L * HID * INTER;
        const uint tgt256 = 256u * (L + 1), tgt32 = 32u * (L + 1);

        // ---- P1: q rows (Wq in regs) + fused partial scores for OWN kvw strip ----
        block_rms_norm(h, n1w + L * HID, buf, aux);
        {
            const float4* X4 = (const float4*)(buf + half * 1024);
            float acc = 0.f;
#pragma unroll
            for (int k = 0; k < 4; ++k) acc = dot4(qpre[k], X4[k * 64 + lane], acc);
            acc = waveAllSum(acc);
            if (lane == 0) aux[16 + wid] = acc;
            __syncthreads();   // aux ready; buf (x_n) reads done -> reusable
        }
        {   // P2a: part[bid][j] = sum_{i in my 8 rows} q_i * kvw[i][j]
            const float q0 = aux[16 + 4 * grp]     + aux[16 + 4 * grp + 1];
            const float q1 = aux[16 + 4 * grp + 2] + aux[16 + 4 * grp + 3];
            const float* kr = kvw + (size_t)(bid * 8 + 2 * grp) * KVW + j256;
            const float acc = q0 * kr[0] + q1 * kr[KVW];
            float* ps = buf;
            ps[grp * 256 + j256] = acc;
            __syncthreads();
            if (tid < 256)
                st_llc(partial + bid * 256 + tid,
                       ps[tid] + ps[256 + tid] + ps[512 + tid] + ps[768 + tid]);
        }
        arrive_grp(bar, LG0, bid);

        // ---- P2b/c: 32 attention blocks reduce + softmax + ctx ----
        if (bid < 32) {
            wait_grp(bar, LG0, tgt256);
            {   // stage1: sum my 8 partial vectors
                float s = 0.f;
#pragma unroll
                for (int b = 0; b < 2; ++b)
                    s += ld_llc(partial + (size_t)(bid * 8 + grp * 2 + b) * 256 + j256);
                float* ps = buf;
                ps[grp * 256 + j256] = s;
                __syncthreads();
                if (tid < 256)
                    st_llc(partial2 + bid * 256 + tid,
                           ps[tid] + ps[256 + tid] + ps[512 + tid] + ps[768 + tid]);
            }
            arrive_line(bar, LNM);
            wait_line<4>(bar, LNM, tgt32);
            {   // stage2: total scores -> softmax -> ctx strip (64 rows)
                float s = 0.f;
#pragma unroll
                for (int c = 0; c < 8; ++c)
                    s += ld_llc(partial2 + (size_t)(grp * 8 + c) * 256 + j256);
                float* sp = buf;
                sp[grp * 256 + j256] = s;
                __syncthreads();
                float sv = -3.4e38f;
                if (tid < 256) sv = sp[tid] + sp[256 + tid] + sp[512 + tid] + sp[768 + tid];
                float mx = waveAllMax(sv);
                if (lane == 0 && wid < 4) aux[wid] = mx;
                __syncthreads();
                mx = fmaxf(fmaxf(aux[0], aux[1]), fmaxf(aux[2], aux[3]));
                const float e = (tid < 256) ? __expf(sv - mx) : 0.f;
                float ts = waveAllSum(e);
                if (lane == 0 && wid < 4) aux[8 + wid] = ts;
                __syncthreads();
                const float den = aux[8] + aux[9] + aux[10] + aux[11];
                float* pj = buf + 1024;
                if (tid < 256) pj[tid] = e / den;
                __syncthreads();
                const float4* p4  = (const float4*)pj;
                const float4* kv4 = (const float4*)kvw;
#pragma unroll
                for (int r = 0; r < 4; ++r) {
                    const int i = bid * 64 + wid * 4 + r;
                    float a = dot4(kv4[(size_t)i * 64 + lane], p4[lane], 0.f);
                    a = waveAllSum(a);
                    if (lane == 0) st_llc(ctx + i, a);
                }
            }
            arrive_line(bar, LN1);
        }
        // ---- bubble work for ALL blocks: Wo regs + 12-row LDS prefetch ----
        float4 wo[4];
        {
            const float4* Wr = (const float4*)(Wo + (size_t)row8 * HID + half * 1024);
#pragma unroll
            for (int k = 0; k < 4; ++k) { wo[k] = Wr[k * 64 + lane]; PIN4(wo[k]); }
        }
        {   // fill pf slots 0..11 (row-task t = slot): 96 chunks over 16 waves
            float4* pf4 = (float4*)pf;
#pragma unroll
            for (int m = 0; m < 6; ++m) {
                const int c = wid * 6 + m, s = c >> 3, k = c & 7;
                const int jj = bid * 22 + (s >> 1);
                const float4* Wr = (const float4*)(((s & 1) ? Wu : Wg) + (size_t)jj * HID);
                pf4[s * 512 + k * 64 + lane] = Wr[k * 64 + lane];
            }
        }
        wait_line<16>(bar, LN1, tgt32);

        // ---- P3: h[row] += Wo[row,:] @ ctx ----
        {
            buf[2 * tid]     = ld_llc(ctx + 2 * tid);
            buf[2 * tid + 1] = ld_llc(ctx + 2 * tid + 1);
            __syncthreads();
            const float4* X4 = (const float4*)(buf + half * 1024);
            float acc = 0.f;
#pragma unroll
            for (int k = 0; k < 4; ++k) acc = dot4(wo[k], X4[k * 64 + lane], acc);
            acc = waveAllSum(acc);
            if (lane == 0) aux[16 + wid] = acc;
            __syncthreads();
            if (tid < 8) {
                const int r = bid * 8 + tid;
                st_llc(h + r, ld_llc(h + r) + aux[16 + 2 * tid] + aux[16 + 2 * tid + 1]);
            }
        }
        arrive_grp(bar, LG2, bid);
        // issue streamed Wg/Wu rows (tasks 12+wid, 28+wid) into pinned regs NOW
        float4 wga[8], wgb[8];
        {
            const int tA = 12 + wid, tB = 28 + wid;
            const int jA = bid * 22 + (tA >> 1), jB = bid * 22 + (tB >> 1);
            const float4* WA = (const float4*)(((tA & 1) ? Wu : Wg) + (size_t)jA * HID);
            const float4* WB = (const float4*)(((tB & 1) ? Wu : Wg) + (size_t)jB * HID);
#pragma unroll
            for (int k = 0; k < 8; ++k) { wga[k] = WA[k * 64 + lane]; PIN4(wga[k]); }
#pragma unroll
            for (int k = 0; k < 8; ++k) { wgb[k] = WB[k * 64 + lane]; PIN4(wgb[k]); }
        }
        wait_grp(bar, LG2, tgt256);

        // ---- P4: inter = silu(Wg@x2)*(Wu@x2) ----
        block_rms_norm(h, n2w + L * HID, buf, aux);
        {
            float* res = buf + 2048;   // 44 results
            const float4* X4  = (const float4*)buf;
            const float4* pf4 = (const float4*)pf;
            if (wid < 12) {
                float acc = 0.f;
#pragma unroll
                for (int k = 0; k < 8; ++k)
                    acc = dot4(pf4[wid * 512 + k * 64 + lane], X4[k * 64 + lane], acc);
                acc = waveAllSum(acc);
                if (lane == 0) res[wid] = acc;
            }
            float accA = 0.f, accB = 0.f;
#pragma unroll
            for (int k = 0; k < 8; ++k) accA = dot4(wga[k], X4[k * 64 + lane], accA);
#pragma unroll
            for (int k = 0; k < 8; ++k) accB = dot4(wgb[k], X4[k * 64 + lane], accB);
            accA = waveAllSum(accA);
            accB = waveAllSum(accB);
            if (lane == 0) { res[12 + wid] = accA; res[28 + wid] = accB; }
            if (bid == 0) {
                const float* sw = shg_w + L * HID;
                float pv = sw[2 * tid] * buf[2 * tid] + sw[2 * tid + 1] * buf[2 * tid + 1];
                pv = waveAllSum(pv);
                if (lane == 0) aux[32 + wid] = pv;
            }
            __syncthreads();
            if (tid < 22) {
                const float gv = res[2 * tid], uv = res[2 * tid + 1];
                st_llc(inter + bid * 22 + tid, gv / (1.f + __expf(-gv)) * uv);
            }
            if (bid == 0 && tid == 0) {
                float gl = 0.f;
#pragma unroll
                for (int i = 0; i < 16; ++i) gl += aux[32 + i];
                st_llc(gsc, 1.f / (1.f + __expf(-gl)));
            }
        }
        arrive_grp(bar, LG3, bid);
        // prefetch Wd (all of this block's chunk) + next-layer Wq
        float4 dpre[11];
        {
            const float4* Dr = (const float4*)(Wd + (size_t)row8 * INTER + half * 2816);
#pragma unroll
            for (int k = 0; k < 11; ++k) { dpre[k] = Dr[k * 64 + lane]; PIN4(dpre[k]); }
        }
        if (L < NL - 1) {
            const float4* Qn = (const float4*)(q_w + (size_t)(L + 1) * HID * HID +
                                               (size_t)row8 * HID + half * 1024);
#pragma unroll
            for (int k = 0; k < 4; ++k) { qpre[k] = Qn[k * 64 + lane]; PIN4(qpre[k]); }
        }
        wait_grp(bar, LG3, tgt256);

        // ---- P5: h[row] += g * (Wd[row,:] @ inter) ----
        {
#pragma unroll
            for (int k = 0; k < 6; ++k) {
                const int idx = k * 1024 + tid;
                if (idx < INTER) buf[idx] = ld_llc(inter + idx);
            }
            __syncthreads();
            const float gg = ld_llc(gsc);
            const float4* I4 = (const float4*)(buf + half * 2816);
            float acc = 0.f;
#pragma unroll
            for (int k = 0; k < 11; ++k) acc = dot4(dpre[k], I4[k * 64 + lane], acc);
            acc = waveAllSum(acc);
            if (lane == 0) aux[16 + wid] = acc;
            __syncthreads();
            if (tid < 8) {
                const int r = bid * 8 + tid;
                const float v = ld_llc(h + r) + gg * (aux[16 + 2 * tid] + aux[16 + 2 * tid + 1]);
                if (L == NL - 1) out[r] = v;
                else st_llc(h + r, v);
            }
        }
        if (L < NL - 1) {
            arrive_grp(bar, LG4, bid);
            wait_grp(bar, LG4, tgt256);
        }
    }
}

// ---------------- host ----------------
extern "C" void kernel_launch(void* const* d_in, const int* in_sizes, int n_in,
                              void* d_out, int out_size, void* d_ws, size_t ws_size,
                              hipStream_t stream) {
    const float* x     = (const float*)d_in[0];
    const float* kvw   = (const float*)d_in[1];
    const float* n1w   = (const float*)d_in[2];
    const float* n2w   = (const float*)d_in[3];
    const float* q_w   = (const float*)d_in[4];
    // d_in[5]=k_w, d_in[6]=v_w: dead in reference
    const float* o_w   = (const float*)d_in[7];
    // d_in[8]=router_w: dead
    const float* shg_w = (const float*)d_in[9];
    const float* g_w   = (const float*)d_in[10];
    const float* u_w   = (const float*)d_in[11];
    const float* dn_w  = (const float*)d_in[12];
    float* out = (float*)d_out;
    float* ws  = (float*)d_ws;

    k_init<<<1, 1024, 0, stream>>>(x, ws);
    k_backbone<<<NB, NT, 0, stream>>>(kvw, n1w, n2w, q_w, o_w, shg_w,
                                      g_w, u_w, dn_w, out, ws);
}

// Round 8
// 441.080 us; speedup vs baseline: 1.2086x; 1.2086x over previous
//
#include <hip/hip_runtime.h>

#define HID 2048
#define INTER 5632
#define KVW 256
#define NL 6
#define RMS_EPS 1e-6f

#define NB 256     // 1 block per CU (118KB LDS forces exclusivity)
#define NT 1024    // 16 waves

typedef unsigned int uint;

// ---- barrier lines: 4KB apart to spread across LLC slices ----
#define LSTRIDE 1024          // uints between lines (4KB)
#define LG0 0                 // 16 lines: partials ready   (256 arrivals/layer)
#define LG2 16                // 16 lines: h' ready         (256/layer)
#define LG3 32                // 16 lines: inter ready      (256/layer)
#define LG4 48                // 16 lines: h'' ready        (256/layer)
#define LN1 64                // 8 lines:  ctx ready        (32/layer)
#define LNM 72                // 8 lines:  partial2 ready   (32/layer)
#define BAR_UINTS (80 * 1024) // 320KB

// ---- ws float offsets ----
#define F_H     (BAR_UINTS)
#define F_CTX   (F_H + 2048)
#define F_PART  (F_CTX + 2048)     // 256*256
#define F_PART2 (F_PART + 65536)   // 32*256
#define F_INTER (F_PART2 + 8192)   // 5632
#define F_GSC   (F_INTER + 5632)

// ---------------- LLC (relaxed agent-scope) access ----------------
__device__ __forceinline__ float ld_llc(const float* p) {
    return __hip_atomic_load(p, __ATOMIC_RELAXED, __HIP_MEMORY_SCOPE_AGENT);
}
__device__ __forceinline__ void st_llc(float* p, float v) {
    __hip_atomic_store(p, v, __ATOMIC_RELAXED, __HIP_MEMORY_SCOPE_AGENT);
}

// ---------------- wave helpers ----------------
__device__ __forceinline__ float waveAllSum(float v) {
#pragma unroll
    for (int m = 32; m > 0; m >>= 1) v += __shfl_xor(v, m, 64);
    return v;
}
__device__ __forceinline__ float waveAllMax(float v) {
#pragma unroll
    for (int m = 32; m > 0; m >>= 1) v = fmaxf(v, __shfl_xor(v, m, 64));
    return v;
}
__device__ __forceinline__ float dot4(float4 a, float4 b, float acc) {
    acc = fmaf(a.x, b.x, acc);
    acc = fmaf(a.y, b.y, acc);
    acc = fmaf(a.z, b.z, acc);
    acc = fmaf(a.w, b.w, acc);
    return acc;
}

// ---------------- split monotonic barriers (arrive early, wait late) ----------------
// __syncthreads in arrive drains vmcnt, so this block's sc1 data stores are at
// the LLC before the arrival add; waiters poll the arrival lines directly.
__device__ __forceinline__ void arrive16(uint* bar, int grpLine, int bid) {
    __syncthreads();
    if (threadIdx.x == 0)
        __hip_atomic_fetch_add(bar + (grpLine + (bid & 15)) * LSTRIDE, 1u,
                               __ATOMIC_RELAXED, __HIP_MEMORY_SCOPE_AGENT);
}
template <int SLP>
__device__ __forceinline__ void wait16(const uint* bar, int grpLine, uint target) {
    if (threadIdx.x < 16) {
        const uint* p = bar + (grpLine + threadIdx.x) * LSTRIDE;
        while (true) {
            uint v = __hip_atomic_load(p, __ATOMIC_RELAXED, __HIP_MEMORY_SCOPE_AGENT);
#pragma unroll
            for (int m = 8; m > 0; m >>= 1) v += __shfl_xor(v, m, 64);
            if (v >= target) break;
            __builtin_amdgcn_s_sleep(SLP);
        }
    }
    __syncthreads();
}
__device__ __forceinline__ void arrive8(uint* bar, int grpLine, int bid) {
    __syncthreads();
    if (threadIdx.x == 0)
        __hip_atomic_fetch_add(bar + (grpLine + (bid & 7)) * LSTRIDE, 1u,
                               __ATOMIC_RELAXED, __HIP_MEMORY_SCOPE_AGENT);
}
template <int SLP>
__device__ __forceinline__ void wait8(const uint* bar, int grpLine, uint target) {
    if (threadIdx.x < 8) {
        const uint* p = bar + (grpLine + threadIdx.x) * LSTRIDE;
        while (true) {
            uint v = __hip_atomic_load(p, __ATOMIC_RELAXED, __HIP_MEMORY_SCOPE_AGENT);
#pragma unroll
            for (int m = 4; m > 0; m >>= 1) v += __shfl_xor(v, m, 64);
            if (v >= target) break;
            __builtin_amdgcn_s_sleep(SLP);
        }
    }
    __syncthreads();
}

// rmsnorm(h, nw) -> xbuf[2048]; aux[0..16) scratch
__device__ __forceinline__ void block_rms_norm(const float* __restrict__ h,
                                               const float* __restrict__ nw,
                                               float* xbuf, float* aux) {
    const int tid = threadIdx.x, lane = tid & 63, wid = tid >> 6;
    const float a = ld_llc(h + 2 * tid), b = ld_llc(h + 2 * tid + 1);
    float ss = a * a + b * b;
    ss = waveAllSum(ss);
    if (lane == 0) aux[wid] = ss;
    __syncthreads();
    float tot = 0.f;
#pragma unroll
    for (int i = 0; i < 16; ++i) tot += aux[i];
    const float f = rsqrtf(tot * (1.0f / (float)HID) + RMS_EPS);
    xbuf[2 * tid]     = a * f * nw[2 * tid];
    xbuf[2 * tid + 1] = b * f * nw[2 * tid + 1];
    __syncthreads();
}

// ---------------- init ----------------
__global__ __launch_bounds__(1024) void k_init(const float* __restrict__ x,
                                               float* __restrict__ ws) {
    uint* bar = (uint*)ws;
#pragma unroll
    for (int k = 0; k < 80; ++k) bar[k * 1024 + threadIdx.x] = 0u;
    float* h = ws + F_H;
    h[threadIdx.x] = x[threadIdx.x];
    h[1024 + threadIdx.x] = x[1024 + threadIdx.x];
}

// ---------------- persistent backbone ----------------
__global__ __launch_bounds__(NT) void k_backbone(
    const float* __restrict__ kvw,
    const float* __restrict__ n1w, const float* __restrict__ n2w,
    const float* __restrict__ q_w, const float* __restrict__ o_w,
    const float* __restrict__ shg_w,
    const float* __restrict__ g_w, const float* __restrict__ u_w,
    const float* __restrict__ dn_w,
    float* __restrict__ out, float* __restrict__ ws) {
    __shared__ float stage[24576];   // 96KB: Wq -> WgWu -> Wd rotating stage
    __shared__ float buf[5632];
    __shared__ float aux[64];

    uint*  bar      = (uint*)ws;
    float* h        = ws + F_H;
    float* ctx      = ws + F_CTX;
    float* partial  = ws + F_PART;
    float* partial2 = ws + F_PART2;
    float* inter    = ws + F_INTER;
    float* gsc      = ws + F_GSC;

    const int bid  = blockIdx.x;
    const int tid  = threadIdx.x;
    const int lane = tid & 63, wid = tid >> 6;
    const int half = wid & 1;
    const int j256 = tid & 255, grp = tid >> 8;

    // stage layer-0 Wq slice (8 rows x 2048 = 64 chunks of 256 floats)
    {
        const float* Wq0 = q_w;
#pragma unroll
        for (int m_ = 0; m_ < 4; ++m_) {
            const int m = wid + m_ * 16;           // 0..63
            const int r = m >> 3, c = m & 7;
            const float* src = Wq0 + (size_t)(bid * 8 + r) * HID + c * 256;
            ((float4*)(stage + m * 256))[lane] = ((const float4*)src)[lane];
        }
    }

    for (int L = 0; L < NL; ++L) {
        const float* Wo = o_w  + (size_t)L * HID * HID;
        const float* Wg = g_w  + (size_t)L * INTER * HID;
        const float* Wu = u_w  + (size_t)L * INTER * HID;
        const float* Wd = dn_w + (size_t)L * HID * INTER;
        const uint tgt256 = 256u * (L + 1), tgt32 = 32u * (L + 1);

        // ---- P1: q (8 rows, Wq fully staged in LDS) + fused partial scores ----
        block_rms_norm(h, n1w + L * HID, buf, aux);   // syncthreads drains stage loads
        {
            const float4* X4 = (const float4*)buf;
            const float4* S4 = (const float4*)stage;
            const int r = wid >> 1;
            float acc = 0.f;
#pragma unroll
            for (int k = 0; k < 4; ++k) {
                const int c = half * 4 + k;
                acc = dot4(S4[(r * 8 + c) * 64 + lane], X4[c * 64 + lane], acc);
            }
            acc = waveAllSum(acc);
            if (lane == 0) aux[16 + wid] = acc;
            __syncthreads();
        }
        {   // partial[bid][j] = sum over this block's 8 q rows
            const float q0 = aux[16 + 4 * grp]     + aux[16 + 4 * grp + 1];
            const float q1 = aux[16 + 4 * grp + 2] + aux[16 + 4 * grp + 3];
            const float* kr = kvw + (size_t)(bid * 8 + 2 * grp) * KVW + j256;
            float* ps = buf;
            ps[grp * 256 + j256] = q0 * kr[0] + q1 * kr[KVW];
            __syncthreads();
            if (tid < 256)
                st_llc(partial + bid * 256 + tid,
                       ps[tid] + ps[256 + tid] + ps[512 + tid] + ps[768 + tid]);
        }
        arrive16(bar, LG0, bid);

        // ---- P2: 32 attention blocks ----
        if (bid < 32) {
            wait16<8>(bar, LG0, tgt256);
            {   // stage1: sum my 8 partial vectors -> partial2
                float s = 0.f;
#pragma unroll
                for (int b = 0; b < 2; ++b)
                    s += ld_llc(partial + (size_t)(bid * 8 + grp * 2 + b) * 256 + j256);
                float* ps = buf;
                ps[grp * 256 + j256] = s;
                __syncthreads();
                if (tid < 256)
                    st_llc(partial2 + bid * 256 + tid,
                           ps[tid] + ps[256 + tid] + ps[512 + tid] + ps[768 + tid]);
            }
            arrive8(bar, LNM, bid);
            wait8<4>(bar, LNM, tgt32);
            {   // stage2: total scores -> softmax -> ctx strip (64 rows)
                float s = 0.f;
#pragma unroll
                for (int c = 0; c < 8; ++c)
                    s += ld_llc(partial2 + (size_t)(grp * 8 + c) * 256 + j256);
                float* sp = buf;
                sp[grp * 256 + j256] = s;
                __syncthreads();
                float sv = -3.4e38f;
                if (tid < 256) sv = sp[tid] + sp[256 + tid] + sp[512 + tid] + sp[768 + tid];
                float mx = waveAllMax(sv);
                if (lane == 0 && wid < 4) aux[wid] = mx;
                __syncthreads();
                mx = fmaxf(fmaxf(aux[0], aux[1]), fmaxf(aux[2], aux[3]));
                const float e = (tid < 256) ? __expf(sv - mx) : 0.f;
                float ts = waveAllSum(e);
                if (lane == 0 && wid < 4) aux[8 + wid] = ts;
                __syncthreads();
                const float den = aux[8] + aux[9] + aux[10] + aux[11];
                float* pj = buf + 1024;
                if (tid < 256) pj[tid] = e / den;
                __syncthreads();
                const float4* p4  = (const float4*)pj;
                const float4* kv4 = (const float4*)kvw;
#pragma unroll
                for (int r2 = 0; r2 < 4; ++r2) {
                    const int i = bid * 64 + wid * 4 + r2;
                    float a = dot4(kv4[(size_t)i * 64 + lane], p4[lane], 0.f);
                    a = waveAllSum(a);
                    if (lane == 0) st_llc(ctx + i, a);
                }
            }
            arrive8(bar, LN1, bid);
        }
        // ---- all blocks: stage Wg/Wu chunks 0,1 of all 44 row-tasks (88KB) ----
        {
#pragma unroll
            for (int m_ = 0; m_ < 6; ++m_) {
                const int m = wid + m_ * 16;
                if (m < 88) {
                    const int t = m >> 1, c = m & 1;
                    const int jj = bid * 22 + (t >> 1);
                    const float* src = (((t & 1) ? Wu : Wg) + (size_t)jj * HID) + c * 256;
                    ((float4*)(stage + m * 256))[lane] = ((const float4*)src)[lane];
                }
            }
        }
        wait8<16>(bar, LN1, tgt32);

        // ---- P3: h[row] += Wo[row,:] @ ctx (Wo streamed live) ----
        {
            buf[2 * tid]     = ld_llc(ctx + 2 * tid);
            buf[2 * tid + 1] = ld_llc(ctx + 2 * tid + 1);
            __syncthreads();
            const int r = wid >> 1;
            const float4* Wr = (const float4*)(Wo + (size_t)(bid * 8 + r) * HID + half * 1024);
            const float4* X4 = (const float4*)(buf + half * 1024);
            float acc = 0.f;
#pragma unroll
            for (int k = 0; k < 4; ++k) acc = dot4(Wr[k * 64 + lane], X4[k * 64 + lane], acc);
            acc = waveAllSum(acc);
            if (lane == 0) aux[16 + wid] = acc;
            __syncthreads();
            if (tid < 8) {
                const int rr = bid * 8 + tid;
                st_llc(h + rr, ld_llc(h + rr) + aux[16 + 2 * tid] + aux[16 + 2 * tid + 1]);
            }
        }
        arrive16(bar, LG2, bid);
        wait16<16>(bar, LG2, tgt256);

        // ---- P4: inter = silu(Wg@x2)*(Wu@x2); chunks 0,1 from LDS, 2..7 live ----
        block_rms_norm(h, n2w + L * HID, buf, aux);
        {
            float* res = buf + 2048;   // 44 results
            const float4* X4 = (const float4*)buf;
            const float4* S4 = (const float4*)stage;
            for (int t = wid; t < 44; t += 16) {
                const int jj = bid * 22 + (t >> 1);
                const float* Wrow = ((t & 1) ? Wu : Wg) + (size_t)jj * HID;
                float acc = 0.f;
                acc = dot4(S4[(t * 2) * 64 + lane],     X4[lane],      acc);
                acc = dot4(S4[(t * 2 + 1) * 64 + lane], X4[64 + lane], acc);
#pragma unroll
                for (int c = 2; c < 8; ++c)
                    acc = dot4(((const float4*)Wrow)[c * 64 + lane], X4[c * 64 + lane], acc);
                acc = waveAllSum(acc);
                if (lane == 0) res[t] = acc;
            }
            if (bid == 0) {
                const float* sw = shg_w + L * HID;
                float pv = sw[2 * tid] * buf[2 * tid] + sw[2 * tid + 1] * buf[2 * tid + 1];
                pv = waveAllSum(pv);
                if (lane == 0) aux[32 + wid] = pv;
            }
            __syncthreads();
            if (tid < 22) {
                const float gv = res[2 * tid], uv = res[2 * tid + 1];
                st_llc(inter + bid * 22 + tid, gv / (1.f + __expf(-gv)) * uv);
            }
            if (bid == 0 && tid == 0) {
                float gl = 0.f;
#pragma unroll
                for (int i = 0; i < 16; ++i) gl += aux[32 + i];
                st_llc(gsc, 1.f / (1.f + __expf(-gl)));
            }
        }
        arrive16(bar, LG3, bid);
        // ---- stage Wd: 8 rows, chunks {0..5} and {11..16} (96KB) ----
        {
#pragma unroll
            for (int m_ = 0; m_ < 6; ++m_) {
                const int m = wid + m_ * 16;       // 0..95
                const int r = m / 12, cc = m % 12;
                const int c = (cc < 6) ? cc : cc + 5;
                const float* src = Wd + (size_t)(bid * 8 + r) * INTER + c * 256;
                ((float4*)(stage + m * 256))[lane] = ((const float4*)src)[lane];
            }
        }
        wait16<16>(bar, LG3, tgt256);

        // ---- P5: h[row] += g * (Wd[row,:] @ inter); 11/22 chunks from LDS ----
        {
#pragma unroll
            for (int k = 0; k < 6; ++k) {
                const int idx = k * 1024 + tid;
                if (idx < INTER) buf[idx] = ld_llc(inter + idx);
            }
            __syncthreads();
            const float gg = ld_llc(gsc);
            const int r = wid >> 1;
            const float* Drow = Wd + (size_t)(bid * 8 + r) * INTER;
            const float4* I4 = (const float4*)buf;
            const float4* S4 = (const float4*)stage;
            float acc = 0.f;
            if (half == 0) {
#pragma unroll
                for (int c = 0; c < 6; ++c)
                    acc = dot4(S4[(r * 12 + c) * 64 + lane], I4[c * 64 + lane], acc);
#pragma unroll
                for (int c = 6; c < 11; ++c)
                    acc = dot4(((const float4*)Drow)[c * 64 + lane], I4[c * 64 + lane], acc);
            } else {
#pragma unroll
                for (int c = 11; c < 17; ++c)
                    acc = dot4(S4[(r * 12 + 6 + (c - 11)) * 64 + lane], I4[c * 64 + lane], acc);
#pragma unroll
                for (int c = 17; c < 22; ++c)
                    acc = dot4(((const float4*)Drow)[c * 64 + lane], I4[c * 64 + lane], acc);
            }
            acc = waveAllSum(acc);
            if (lane == 0) aux[16 + wid] = acc;
            __syncthreads();
            if (tid < 8) {
                const int rr = bid * 8 + tid;
                const float v = ld_llc(h + rr) + gg * (aux[16 + 2 * tid] + aux[16 + 2 * tid + 1]);
                if (L == NL - 1) out[rr] = v;
                else st_llc(h + rr, v);
            }
        }
        if (L < NL - 1) {
            arrive16(bar, LG4, bid);
            // ---- stage next-layer Wq slice (64KB) during the h''-wait ----
            const float* Wqn = q_w + (size_t)(L + 1) * HID * HID;
#pragma unroll
            for (int m_ = 0; m_ < 4; ++m_) {
                const int m = wid + m_ * 16;
                const int r = m >> 3, c = m & 7;
                const float* src = Wqn + (size_t)(bid * 8 + r) * HID + c * 256;
                ((float4*)(stage + m * 256))[lane] = ((const float4*)src)[lane];
            }
            wait16<16>(bar, LG4, tgt256);
        }
    }
}

// ---------------- host ----------------
extern "C" void kernel_launch(void* const* d_in, const int* in_sizes, int n_in,
                              void* d_out, int out_size, void* d_ws, size_t ws_size,
                              hipStream_t stream) {
    const float* x     = (const float*)d_in[0];
    const float* kvw   = (const float*)d_in[1];
    const float* n1w   = (const float*)d_in[2];
    const float* n2w   = (const float*)d_in[3];
    const float* q_w   = (const float*)d_in[4];
    // d_in[5]=k_w, d_in[6]=v_w: dead in reference
    const float* o_w   = (const float*)d_in[7];
    // d_in[8]=router_w: dead
    const float* shg_w = (const float*)d_in[9];
    const float* g_w   = (const float*)d_in[10];
    const float* u_w   = (const float*)d_in[11];
    const float* dn_w  = (const float*)d_in[12];
    float* out = (float*)d_out;
    float* ws  = (float*)d_ws;

    k_init<<<1, 1024, 0, stream>>>(x, ws);
    k_backbone<<<NB, NT, 0, stream>>>(kvw, n1w, n2w, q_w, o_w, shg_w,
                                      g_w, u_w, dn_w, out, ws);
}